// Round 6
// baseline (469.394 us; speedup 1.0000x reference)
//
#include <hip/hip_runtime.h>
#include <hip/hip_bf16.h>

typedef __bf16 bf16x8 __attribute__((ext_vector_type(8)));
typedef float  f32x4  __attribute__((ext_vector_type(4)));
typedef float  f32x16 __attribute__((ext_vector_type(16)));

#define B_  512
#define DX_ 128
#define H_  512

// ---------------------------------------------------------------------------
// prep:
//  blocks 0..127   : pack W2 -> c-major (C=64) 32x32x16 B-frag layout
//                    PW2c[c8][ks2][nt2][lane][8]
//                    col = c*64 + nt2*32 + (lane&31), k = ks2*16 + (lane>>5)*8 + j
//  blocks 128..191 : hx = x@W1x ; hyb = y@W1y + b1 (fp32 out)  [verified]
// ---------------------------------------------------------------------------
__global__ __launch_bounds__(256) void prep_kernel(
    const float* __restrict__ x, const float* __restrict__ y,
    const float* __restrict__ W1, const float* __restrict__ W2,
    const float* __restrict__ b1,
    __bf16* __restrict__ PW2c, float* __restrict__ hx, float* __restrict__ hyb)
{
    int blk = blockIdx.x;
    int tid = threadIdx.x;
    if (blk < 128) {
        int u    = blk * 256 + tid;           // 0..32767
        int ks2  = u >> 10;                   // 0..31
        int rem  = u & 1023;
        int nt16 = rem >> 6;                  // 0..15 (32-col tiles)
        int l    = rem & 63;
        int k    = ks2 * 16 + ((l >> 5) << 3);
        int col  = nt16 * 32 + (l & 31);
        const float* p = W2 + k * H_ + col;
        bf16x8 v;
        #pragma unroll
        for (int j = 0; j < 8; ++j) v[j] = (__bf16)p[j * H_];
        int c   = nt16 >> 1, nt2 = nt16 & 1;
        int dst = c * 32768 + ((ks2 * 2 + nt2) * 64 + l) * 8;
        *(bf16x8*)(PW2c + dst) = v;
        return;
    }
    int b    = blk - 128;
    int task = b >> 5;
    int rem  = b & 31;
    int bm   = rem >> 2, bn = rem & 3;
    const float* A  = task ? y : x;
    const float* Wp = W1 + task * DX_ * H_;
    float* outp = task ? hyb : hx;
    int w = tid >> 6, lane = tid & 63;

    f32x4 acc[4][2] = {};
    #pragma unroll
    for (int ks = 0; ks < 4; ++ks) {
        int k0 = ks * 32 + ((lane >> 4) << 3);
        bf16x8 af[4];
        #pragma unroll
        for (int mt = 0; mt < 4; ++mt) {
            int row = bm * 64 + mt * 16 + (lane & 15);
            const float* pa = A + row * DX_ + k0;
            f32x4 q0 = *(const f32x4*)pa;
            f32x4 q1 = *(const f32x4*)(pa + 4);
            #pragma unroll
            for (int j = 0; j < 4; ++j) {
                af[mt][j]     = (__bf16)q0[j];
                af[mt][j + 4] = (__bf16)q1[j];
            }
        }
        #pragma unroll
        for (int nt = 0; nt < 2; ++nt) {
            int col = bn * 128 + (w * 2 + nt) * 16 + (lane & 15);
            const float* pb = Wp + k0 * H_ + col;
            bf16x8 bv;
            #pragma unroll
            for (int j = 0; j < 8; ++j) bv[j] = (__bf16)pb[j * H_];
            #pragma unroll
            for (int mt = 0; mt < 4; ++mt)
                acc[mt][nt] = __builtin_amdgcn_mfma_f32_16x16x32_bf16(af[mt], bv, acc[mt][nt], 0, 0, 0);
        }
    }
    #pragma unroll
    for (int nt = 0; nt < 2; ++nt) {
        int col = bn * 128 + (w * 2 + nt) * 16 + (lane & 15);
        float badd = task ? b1[col] : 0.f;
        #pragma unroll
        for (int mt = 0; mt < 4; ++mt) {
            #pragma unroll
            for (int r = 0; r < 4; ++r) {
                int row = bm * 64 + mt * 16 + ((lane >> 4) << 2) + r;
                outp[row * H_ + col] = acc[mt][nt][r] + badd;
            }
        }
    }
}

// ---------------------------------------------------------------------------
// critic v6: occupancy-first. Block (512 thr, 8 waves) owns a 64-col W2
// slice, staged ONCE into 64KB LDS (2 blocks/CU -> 4 waves/SIMD, forced by
// __launch_bounds__(512,4): 64 AGPR acc + <=64 VGPR). Barrier-free K-loop:
// A = relu(hx+hy)->bf16 built in registers from per-lane global loads
// (imm-offset, L2-resident); B via ds_read_b128 (reg-reused across mt=2).
// 4 latency streams/SIMD now cover the ~250cy L2 latency under the 515cy
// MFMA window. Epilogue: butterfly reduce + atomicAdd of 8 c-slice partials.
// ---------------------------------------------------------------------------
__global__ __launch_bounds__(512, 4) void critic_kernel(
    const float* __restrict__ hx, const float* __restrict__ hyb,
    const __bf16* __restrict__ PW2c,
    const float* __restrict__ b2, const float* __restrict__ W3,
    const float* __restrict__ b3, float* __restrict__ out)
{
    __shared__ __align__(16) char Bs[65536];      // 64 cols x K=512 bf16 frags

    int tid  = threadIdx.x;
    int lane = tid & 63;
    int w    = tid >> 6;                          // wave 0..7
    int blk  = blockIdx.x;                        // 0..4095
    int rb   = blk >> 3;                          // row-block 0..511
    int c    = blk & 7;                           // col-slice (64 cols)
    int ibh  = rb >> 3;                           // i-range [ibh*8, +8)
    int jbh  = rb & 7;                            // j-window [jbh*64, +64)

    int o   = lane >> 5;                          // k-octet selector
    int r31 = lane & 31;

    // ---- stage B slice: 64KB linear, 8 x global_load_lds_dwordx4 / thread
    {
        const __bf16* src = PW2c + c * 32768 + (w * 64 + lane) * 8;
        char* dst_base = Bs + w * 1024;           // + HW lane*16
        #pragma unroll
        for (int i = 0; i < 8; ++i)
            __builtin_amdgcn_global_load_lds(
                (const __attribute__((address_space(1))) void*)(src + i * 4096),
                (__attribute__((address_space(3))) void*)(dst_base + i * 8192),
                16, 0, 0);
    }

    // per-lane A sources (verified mapping):
    // pair-row p = mt*32 + r31 -> i_local = mt*4 + (r31>>3), j_local = lane&7
    const float* hx0 = hx  + (ibh * 8 + (r31 >> 3)) * H_ + o * 8;
    const float* hx1 = hx0 + 4 * H_;
    const float* hyp = hyb + (jbh * 64 + w * 8 + (lane & 7)) * H_ + o * 8;

    f32x16 acc[2][2] = {};
    const f32x4 z4 = {0.f, 0.f, 0.f, 0.f};

    __syncthreads();                              // staging complete (once)

    #pragma unroll
    for (int s = 0; s < 32; ++s) {                // K-16 steps, no barriers
        f32x4 a0  = *(const f32x4*)(hx0 + s * 16);
        f32x4 a1  = *(const f32x4*)(hx0 + s * 16 + 4);
        f32x4 b0  = *(const f32x4*)(hx1 + s * 16);
        f32x4 b1v = *(const f32x4*)(hx1 + s * 16 + 4);
        f32x4 c0  = *(const f32x4*)(hyp + s * 16);
        f32x4 c1  = *(const f32x4*)(hyp + s * 16 + 4);
        f32x4 s00 = __builtin_elementwise_max(a0 + c0, z4);
        f32x4 s01 = __builtin_elementwise_max(a1 + c1, z4);
        f32x4 s10 = __builtin_elementwise_max(b0 + c0, z4);
        f32x4 s11 = __builtin_elementwise_max(b1v + c1, z4);
        bf16x8 am0, am1;
        #pragma unroll
        for (int j = 0; j < 4; ++j) {
            am0[j]     = (__bf16)s00[j];
            am0[j + 4] = (__bf16)s01[j];
            am1[j]     = (__bf16)s10[j];
            am1[j + 4] = (__bf16)s11[j];
        }
        __builtin_amdgcn_s_setprio(1);
        #pragma unroll
        for (int nt = 0; nt < 2; ++nt) {
            bf16x8 bv = *(const bf16x8*)(Bs + ((s * 2 + nt) * 64 + lane) * 16);
            acc[0][nt] = __builtin_amdgcn_mfma_f32_32x32x16_bf16(am0, bv, acc[0][nt], 0, 0, 0);
            acc[1][nt] = __builtin_amdgcn_mfma_f32_32x32x16_bf16(am1, bv, acc[1][nt], 0, 0, 0);
        }
        __builtin_amdgcn_s_setprio(0);
    }

    // ---- epilogue (verified mapping): partial score over this c-slice
    float b2v[2], w3v[2];
    #pragma unroll
    for (int nt = 0; nt < 2; ++nt) {
        int col = c * 64 + nt * 32 + r31;
        b2v[nt] = b2[col];
        w3v[nt] = W3[col];
    }
    float bq = 0.125f * b3[0];
    #pragma unroll
    for (int mt = 0; mt < 2; ++mt) {
        #pragma unroll
        for (int rg = 0; rg < 16; ++rg) {
            float s = 0.f;
            #pragma unroll
            for (int nt = 0; nt < 2; ++nt)
                s += fmaxf(acc[mt][nt][rg] + b2v[nt], 0.f) * w3v[nt];
            s += __shfl_xor(s, 1);
            s += __shfl_xor(s, 2);
            s += __shfl_xor(s, 4);
            s += __shfl_xor(s, 8);
            s += __shfl_xor(s, 16);
            if (r31 == 0) {
                int pl = mt * 32 + (rg & 3) + 8 * (rg >> 2) + (o << 2);
                int i  = ibh * 8 + (pl >> 3);
                int j  = jbh * 64 + w * 8 + (pl & 7);
                atomicAdd(&out[i * B_ + j], s + bq);
            }
        }
    }
}

// ---------------------------------------------------------------------------
extern "C" void kernel_launch(void* const* d_in, const int* in_sizes, int n_in,
                              void* d_out, int out_size, void* d_ws, size_t ws_size,
                              hipStream_t stream)
{
    const float* x  = (const float*)d_in[0];
    const float* y  = (const float*)d_in[1];
    const float* W1 = (const float*)d_in[2];
    const float* b1 = (const float*)d_in[3];
    const float* W2 = (const float*)d_in[4];
    const float* b2 = (const float*)d_in[5];
    const float* W3 = (const float*)d_in[6];
    const float* b3 = (const float*)d_in[7];
    float* out = (float*)d_out;

    char* ws = (char*)d_ws;
    float*  hx   = (float*)(ws);                   // 1 MB
    float*  hyb  = (float*)(ws + 1048576);         // 1 MB
    __bf16* PW2c = (__bf16*)(ws + 2097152);        // 512 KB (end: 2.5 MB)

    hipMemsetAsync(d_out, 0, (size_t)out_size * sizeof(float), stream);
    hipLaunchKernelGGL(prep_kernel, dim3(192), dim3(256), 0, stream,
                       x, y, W1, W2, b1, PW2c, hx, hyb);
    hipLaunchKernelGGL(critic_kernel, dim3(4096), dim3(512), 0, stream,
                       hx, hyb, PW2c, b2, W3, b3, out);
}

// Round 11
// 256.557 us; speedup vs baseline: 1.8296x; 1.8296x over previous
//
#include <hip/hip_runtime.h>
#include <hip/hip_bf16.h>

typedef __bf16 bf16x8 __attribute__((ext_vector_type(8)));
typedef float  f32x4  __attribute__((ext_vector_type(4)));
typedef float  f32x16 __attribute__((ext_vector_type(16)));

#define B_  512
#define DX_ 128
#define H_  512

// ---------------------------------------------------------------------------
// prep (VERBATIM, verified R5/R6):
//  blocks 0..127   : pack W2 -> c-major (C=64) 32x32x16 B-frag layout
//                    PW2c[c8][ks2][nt2][lane][8]
//                    col = c*64 + nt2*32 + (lane&31), k = ks2*16 + (lane>>5)*8 + j
//  blocks 128..191 : hx = x@W1x ; hyb = y@W1y + b1 (fp32 out)
// ---------------------------------------------------------------------------
__global__ __launch_bounds__(256) void prep_kernel(
    const float* __restrict__ x, const float* __restrict__ y,
    const float* __restrict__ W1, const float* __restrict__ W2,
    const float* __restrict__ b1,
    __bf16* __restrict__ PW2c, float* __restrict__ hx, float* __restrict__ hyb)
{
    int blk = blockIdx.x;
    int tid = threadIdx.x;
    if (blk < 128) {
        int u    = blk * 256 + tid;           // 0..32767
        int ks2  = u >> 10;                   // 0..31
        int rem  = u & 1023;
        int nt16 = rem >> 6;                  // 0..15 (32-col tiles)
        int l    = rem & 63;
        int k    = ks2 * 16 + ((l >> 5) << 3);
        int col  = nt16 * 32 + (l & 31);
        const float* p = W2 + k * H_ + col;
        bf16x8 v;
        #pragma unroll
        for (int j = 0; j < 8; ++j) v[j] = (__bf16)p[j * H_];
        int c   = nt16 >> 1, nt2 = nt16 & 1;
        int dst = c * 32768 + ((ks2 * 2 + nt2) * 64 + l) * 8;
        *(bf16x8*)(PW2c + dst) = v;
        return;
    }
    int b    = blk - 128;
    int task = b >> 5;
    int rem  = b & 31;
    int bm   = rem >> 2, bn = rem & 3;
    const float* A  = task ? y : x;
    const float* Wp = W1 + task * DX_ * H_;
    float* outp = task ? hyb : hx;
    int w = tid >> 6, lane = tid & 63;

    f32x4 acc[4][2] = {};
    #pragma unroll
    for (int ks = 0; ks < 4; ++ks) {
        int k0 = ks * 32 + ((lane >> 4) << 3);
        bf16x8 af[4];
        #pragma unroll
        for (int mt = 0; mt < 4; ++mt) {
            int row = bm * 64 + mt * 16 + (lane & 15);
            const float* pa = A + row * DX_ + k0;
            f32x4 q0 = *(const f32x4*)pa;
            f32x4 q1 = *(const f32x4*)(pa + 4);
            #pragma unroll
            for (int j = 0; j < 4; ++j) {
                af[mt][j]     = (__bf16)q0[j];
                af[mt][j + 4] = (__bf16)q1[j];
            }
        }
        #pragma unroll
        for (int nt = 0; nt < 2; ++nt) {
            int col = bn * 128 + (w * 2 + nt) * 16 + (lane & 15);
            const float* pb = Wp + k0 * H_ + col;
            bf16x8 bv;
            #pragma unroll
            for (int j = 0; j < 8; ++j) bv[j] = (__bf16)pb[j * H_];
            #pragma unroll
            for (int mt = 0; mt < 4; ++mt)
                acc[mt][nt] = __builtin_amdgcn_mfma_f32_16x16x32_bf16(af[mt], bv, acc[mt][nt], 0, 0, 0);
        }
    }
    #pragma unroll
    for (int nt = 0; nt < 2; ++nt) {
        int col = bn * 128 + (w * 2 + nt) * 16 + (lane & 15);
        float badd = task ? b1[col] : 0.f;
        #pragma unroll
        for (int mt = 0; mt < 4; ++mt) {
            #pragma unroll
            for (int r = 0; r < 4; ++r) {
                int row = bm * 64 + mt * 16 + ((lane >> 4) << 2) + r;
                outp[row * H_ + col] = acc[mt][nt][r] + badd;
            }
        }
    }
}

// ---------------------------------------------------------------------------
// critic v7: latency-first. Block = 256 thr / 4 waves = 64 pairs (8i x 8j)
// x ALL 512 cols (no GEN redundancy, no global atomics). Wave = 64 pairs x
// 128 cols (mt2 x nt4, acc=128) -> 2 waves/SIMD -> 2 independent blocks/CU.
// hx/hy staged once in LDS (row-stride 520: conflict-free broadcast reads);
// h1[64][32]bf16 double-buffered, XOR-swizzled, GEN(c+1) overlaps MFMA(c),
// ONE barrier per K-32 chunk. B streams from packed PW2c via dwordx4 (L2).
// Epilogue: b2/relu/W3 fold, butterfly reduce, LDS-combine across 4 waves.
// ---------------------------------------------------------------------------
__global__ __launch_bounds__(256, 2) void critic_kernel(
    const float* __restrict__ hx, const float* __restrict__ hyb,
    const __bf16* __restrict__ PW2c,
    const float* __restrict__ b2, const float* __restrict__ W3,
    const float* __restrict__ b3, float* __restrict__ out)
{
    __shared__ float xs[16 * 520];                // rows 0..7 hx, 8..15 hy (+8 pad)
    __shared__ __align__(16) char h1b[2][4096];   // [buf][64 pairs][32 k] bf16, swizzled
    __shared__ float sc_s[64];

    int tid  = threadIdx.x;
    int lane = tid & 63;
    int w    = tid >> 6;                          // wave 0..3 = col-group
    int r31  = lane & 31;
    int o    = lane >> 5;
    int blk  = blockIdx.x;
    int ibh  = blk >> 6;                          // i-window [ibh*8, +8)
    int jbh  = blk & 63;                          // j-window [jbh*8, +8)

    // ---- stage hx/hy slices (16 rows x 512 f32), once
    #pragma unroll
    for (int it = 0; it < 8; ++it) {
        int slot = it * 256 + tid;                // 0..2047
        int row  = slot >> 7;
        int c4   = (slot & 127) << 2;
        const float* src = (row < 8) ? &hx[(ibh * 8 + row) * H_ + c4]
                                     : &hyb[(jbh * 8 + (row - 8)) * H_ + c4];
        *(f32x4*)&xs[row * 520 + c4] = *(const f32x4*)src;
    }
    if (tid < 64) sc_s[tid] = 0.f;

    // GEN mapping: thread -> (pair p = tid>>2, k-octet oct = tid&3 within K-32)
    int gp = tid >> 2, goct = tid & 3;
    const float* gi = xs + (gp >> 3) * 520;             // hx row
    const float* gj = xs + (8 + (gp & 7)) * 520;        // hy row
    char* gw = &h1b[0][0] + gp * 64 + ((goct ^ (gp & 3)) << 4);
    const f32x4 z4 = {0.f, 0.f, 0.f, 0.f};

    // A-frag read offsets: step t, tile mt: row p' = mt*32+r31, octet 2t+o
    int aoff[2][2];
    #pragma unroll
    for (int t = 0; t < 2; ++t)
        #pragma unroll
        for (int mt = 0; mt < 2; ++mt) {
            int pr = mt * 32 + r31;
            aoff[t][mt] = pr * 64 + (((2 * t + o) ^ (pr & 3)) << 4);
        }

    // B base (verified R5 pack): el = c*32768 + ((s*2+nt2)*64+lane)*8,
    // c = 2w + (nt>>1), s = chunk*2 + t
    const __bf16* pb0 = PW2c + (2 * w) * 32768 + lane * 8;

    f32x16 acc[2][4] = {};

    auto GEN = [&](int chunk, int buf) {
        int k0 = chunk * 32 + goct * 8;
        f32x4 u0 = *(const f32x4*)(gi + k0);
        f32x4 u1 = *(const f32x4*)(gi + k0 + 4);
        f32x4 v0 = *(const f32x4*)(gj + k0);
        f32x4 v1 = *(const f32x4*)(gj + k0 + 4);
        f32x4 s0 = __builtin_elementwise_max(u0 + v0, z4);
        f32x4 s1 = __builtin_elementwise_max(u1 + v1, z4);
        bf16x8 hv;
        #pragma unroll
        for (int j = 0; j < 4; ++j) {
            hv[j]     = (__bf16)s0[j];
            hv[j + 4] = (__bf16)s1[j];
        }
        *(bf16x8*)(gw + buf * 4096) = hv;
    };

    __syncthreads();                              // xs staged
    GEN(0, 0);
    __syncthreads();                              // buf0 ready

    for (int chunk = 0; chunk < 16; ++chunk) {
        int buf = chunk & 1;
        if (chunk < 15) GEN(chunk + 1, buf ^ 1);  // overlaps MFMA below
        const char* base = &h1b[0][0] + buf * 4096;
        #pragma unroll
        for (int t = 0; t < 2; ++t) {
            int s = chunk * 2 + t;
            bf16x8 a0 = *(const bf16x8*)(base + aoff[t][0]);
            bf16x8 a1 = *(const bf16x8*)(base + aoff[t][1]);
            #pragma unroll
            for (int nt = 0; nt < 4; ++nt) {
                const __bf16* pbv = pb0 + (nt >> 1) * 32768 + (s * 2 + (nt & 1)) * 512;
                bf16x8 bv = *(const bf16x8*)pbv;
                acc[0][nt] = __builtin_amdgcn_mfma_f32_32x32x16_bf16(a0, bv, acc[0][nt], 0, 0, 0);
                acc[1][nt] = __builtin_amdgcn_mfma_f32_32x32x16_bf16(a1, bv, acc[1][nt], 0, 0, 0);
            }
        }
        __syncthreads();                          // GEN(c+1) done & buf reads done
    }

    // ---- epilogue: partial over this wave's 128 cols, combine via sc_s
    float b2v[4], w3v[4];
    #pragma unroll
    for (int nt = 0; nt < 4; ++nt) {
        int col = w * 128 + (nt >> 1) * 64 + (nt & 1) * 32 + r31;
        b2v[nt] = b2[col];
        w3v[nt] = W3[col];
    }
    #pragma unroll
    for (int mt = 0; mt < 2; ++mt) {
        #pragma unroll
        for (int rg = 0; rg < 16; ++rg) {
            float s = 0.f;
            #pragma unroll
            for (int nt = 0; nt < 4; ++nt)
                s += fmaxf(acc[mt][nt][rg] + b2v[nt], 0.f) * w3v[nt];
            s += __shfl_xor(s, 1);
            s += __shfl_xor(s, 2);
            s += __shfl_xor(s, 4);
            s += __shfl_xor(s, 8);
            s += __shfl_xor(s, 16);
            if (r31 == 0) {
                int pr = mt * 32 + (rg & 3) + 8 * (rg >> 2) + (o << 2);  // verified C/D map
                atomicAdd(&sc_s[pr], s);
            }
        }
    }
    __syncthreads();
    if (tid < 64) {
        int i = ibh * 8 + (tid >> 3);
        int j = jbh * 8 + (tid & 7);
        out[i * B_ + j] = sc_s[tid] + b3[0];
    }
}

// ---------------------------------------------------------------------------
extern "C" void kernel_launch(void* const* d_in, const int* in_sizes, int n_in,
                              void* d_out, int out_size, void* d_ws, size_t ws_size,
                              hipStream_t stream)
{
    const float* x  = (const float*)d_in[0];
    const float* y  = (const float*)d_in[1];
    const float* W1 = (const float*)d_in[2];
    const float* b1 = (const float*)d_in[3];
    const float* W2 = (const float*)d_in[4];
    const float* b2 = (const float*)d_in[5];
    const float* W3 = (const float*)d_in[6];
    const float* b3 = (const float*)d_in[7];
    float* out = (float*)d_out;

    char* ws = (char*)d_ws;
    float*  hx   = (float*)(ws);                   // 1 MB
    float*  hyb  = (float*)(ws + 1048576);         // 1 MB
    __bf16* PW2c = (__bf16*)(ws + 2097152);        // 512 KB (end: 2.5 MB)

    hipLaunchKernelGGL(prep_kernel, dim3(192), dim3(256), 0, stream,
                       x, y, W1, W2, b1, PW2c, hx, hyb);
    hipLaunchKernelGGL(critic_kernel, dim3(4096), dim3(256), 0, stream,
                       hx, hyb, PW2c, b2, W3, b3, out);
}